// Round 2
// baseline (102.524 us; speedup 1.0000x reference)
//
#include <hip/hip_runtime.h>
#include <hip/hip_bf16.h>

// MDCA: for each of 4 CAMs [B=128, C=1000, H=14, W=14]:
//   avg_conf[c]  = mean over (b,h,w) of cam[b,c,h,w]
//   avg_count[c] = bincount(target, C)[c] / B
//   out[cam] = mean_c |avg_conf[c] - avg_count[c]|
//
// Memory-bound: 401 MB logical read (~230 MB HBM after L3 retention).
// R1: contiguous-window streaming. Lane i <-> class c0+i (784 B apart);
// each thread streams its class segment sequentially -> each wave sweeps
// a contiguous 50 KB window, blocks tile the tensor contiguously.
// Deterministic: partial sums to ws, fixed reduction order, no float atomics.

constexpr int B   = 128;
constexpr int C   = 1000;
constexpr int HW  = 196;   // 14*14
constexpr int HW4 = 49;    // float4 per (b,c) segment (784 B)

constexpr int NS    = 64;       // b-splits
constexpr int BPS   = B / NS;   // 2 batches per block
constexpr int CHUNK = 256;      // classes per block
constexpr int NCH   = 4;        // ceil(1000/256)

constexpr int G   = 8;          // class groups in stage 2
constexpr int CPG = C / G;      // 125 classes per group

// grid (NCH, NS, 4 cams), block 256. Thread = one class, streams BPS
// segments of 49 float4 each. partial[(cam*NS + s)*C + c] = sum.
__global__ __launch_bounds__(256) void stage1_kernel(
    const float* __restrict__ c0, const float* __restrict__ c1,
    const float* __restrict__ c2, const float* __restrict__ c3,
    float* __restrict__ partial)
{
    const int c   = blockIdx.x * CHUNK + threadIdx.x;
    const int s   = blockIdx.y;
    const int cam = blockIdx.z;
    const float* __restrict__ src =
        (cam == 0) ? c0 : (cam == 1) ? c1 : (cam == 2) ? c2 : c3;
    if (c >= C) return;

    float acc = 0.0f;
    for (int bb = 0; bb < BPS; ++bb) {
        const int b = s * BPS + bb;
        const float4* __restrict__ p =
            reinterpret_cast<const float4*>(src) + (size_t)(b * C + c) * HW4;
        #pragma unroll 7
        for (int j = 0; j < HW4; ++j) {
            const float4 v = p[j];
            acc += (v.x + v.y) + (v.z + v.w);
        }
    }
    partial[(cam * NS + s) * C + c] = acc;
}

// grid 32 (cam = bid>>3, group = bid&7), block 128 (2 waves).
// Reduces NS partials per class (coalesced: fixed k, threads span c),
// builds label histogram in LDS, emits group |.|-sum to ws2[bid].
__global__ __launch_bounds__(128) void stage2_kernel(
    const float* __restrict__ partial, const int* __restrict__ target,
    float* __restrict__ ws2)
{
    __shared__ int   cnt[C];
    __shared__ float red[2];

    const int cam = blockIdx.x >> 3;
    const int g   = blockIdx.x & 7;
    const int tid = threadIdx.x;

    for (int i = tid; i < C; i += 128) cnt[i] = 0;
    __syncthreads();
    if (tid < B) atomicAdd(&cnt[target[tid]], 1);
    __syncthreads();

    float acc = 0.0f;
    if (tid < CPG) {
        const int c = g * CPG + tid;
        float ssum = 0.0f;
        #pragma unroll 8
        for (int k = 0; k < NS; ++k)
            ssum += partial[(cam * NS + k) * C + c];
        acc = fabsf(ssum * (1.0f / (float)(B * HW))
                    - (float)cnt[c] * (1.0f / (float)B));
    }

    #pragma unroll
    for (int off = 32; off > 0; off >>= 1)
        acc += __shfl_down(acc, off, 64);
    if ((tid & 63) == 0) red[tid >> 6] = acc;
    __syncthreads();
    if (tid == 0) ws2[blockIdx.x] = red[0] + red[1];
}

// grid 1, block 64: out[cam] = (sum of its 8 group-sums) / C.
__global__ void stage3_kernel(const float* __restrict__ ws2,
                              float* __restrict__ out)
{
    if (threadIdx.x < 4) {
        float s = 0.0f;
        #pragma unroll
        for (int i = 0; i < G; ++i) s += ws2[threadIdx.x * G + i];
        out[threadIdx.x] = s * (1.0f / (float)C);
    }
}

extern "C" void kernel_launch(void* const* d_in, const int* in_sizes, int n_in,
                              void* d_out, int out_size, void* d_ws, size_t ws_size,
                              hipStream_t stream) {
    const float* c0 = (const float*)d_in[0];
    const float* c1 = (const float*)d_in[1];
    const float* c2 = (const float*)d_in[2];
    const float* c3 = (const float*)d_in[3];
    const int*   target = (const int*)d_in[4];

    float* partial = (float*)d_ws;                    // 4*64*1000 f = 1,024,000 B
    float* ws2     = (float*)((char*)d_ws + 1048576); // 32 floats

    dim3 grid1(NCH, NS, 4);
    stage1_kernel<<<grid1, 256, 0, stream>>>(c0, c1, c2, c3, partial);
    stage2_kernel<<<32, 128, 0, stream>>>(partial, target, ws2);
    stage3_kernel<<<1, 64, 0, stream>>>(ws2, (float*)d_out);
}

// Round 3
// 82.280 us; speedup vs baseline: 1.2460x; 1.2460x over previous
//
#include <hip/hip_runtime.h>
#include <hip/hip_bf16.h>

// MDCA: for each of 4 CAMs [B=128, C=1000, H=14, W=14]:
//   avg_conf[c]  = mean over (b,h,w) of cam[b,c,h,w]
//   avg_count[c] = bincount(target, C)[c] / B
//   out[cam] = mean_c |avg_conf[c] - avg_count[c]|
//
// R2: per-INSTRUCTION coalescing. Thread <-> flat float4 slot k = c*49+j
// within one batch-slab; iterate b per thread (stride 784 KB). Each wave
// instruction reads 1 KB contiguous; grid covers dense 784 KB slabs.
// Stage 1 is deterministic private accumulation; stage 2 folds 49 slots
// per class + histogram + block reduce (L2-resident, ~3 us).

constexpr int B   = 128;
constexpr int C   = 1000;
constexpr int HW  = 196;        // 14*14
constexpr int HW4 = 49;         // float4 per (b,c) segment
constexpr int K4  = C * HW4;    // 49000 float4 per batch-slab per cam

// grid (192, 4 cams), block 256. Thread k sums src[b*K4 + k] over b.
__global__ __launch_bounds__(256) void stage1_kernel(
    const float* __restrict__ c0, const float* __restrict__ c1,
    const float* __restrict__ c2, const float* __restrict__ c3,
    float* __restrict__ partial)
{
    const int k   = blockIdx.x * 256 + threadIdx.x;
    const int cam = blockIdx.y;
    const float* __restrict__ src =
        (cam == 0) ? c0 : (cam == 1) ? c1 : (cam == 2) ? c2 : c3;
    if (k >= K4) return;

    const float4* __restrict__ p = reinterpret_cast<const float4*>(src) + k;

    float4 s0 = {0,0,0,0}, s1 = {0,0,0,0}, s2 = {0,0,0,0}, s3 = {0,0,0,0};
    #pragma unroll 2
    for (int b = 0; b < B; b += 4) {
        const float4 v0 = p[(size_t)(b + 0) * K4];
        const float4 v1 = p[(size_t)(b + 1) * K4];
        const float4 v2 = p[(size_t)(b + 2) * K4];
        const float4 v3 = p[(size_t)(b + 3) * K4];
        s0.x += v0.x; s0.y += v0.y; s0.z += v0.z; s0.w += v0.w;
        s1.x += v1.x; s1.y += v1.y; s1.z += v1.z; s1.w += v1.w;
        s2.x += v2.x; s2.y += v2.y; s2.z += v2.z; s2.w += v2.w;
        s3.x += v3.x; s3.y += v3.y; s3.z += v3.z; s3.w += v3.w;
    }
    const float t0 = (s0.x + s0.y) + (s0.z + s0.w);
    const float t1 = (s1.x + s1.y) + (s1.z + s1.w);
    const float t2 = (s2.x + s2.y) + (s2.z + s2.w);
    const float t3 = (s3.x + s3.y) + (s3.z + s3.w);
    partial[cam * K4 + k] = (t0 + t1) + (t2 + t3);
}

// grid 4 (one block per cam), block 1024. Thread c folds 49 slot-partials,
// LDS histogram for avg_count, block-reduce |diff|, write out[cam].
__global__ __launch_bounds__(1024) void stage2_kernel(
    const float* __restrict__ partial, const int* __restrict__ target,
    float* __restrict__ out)
{
    __shared__ int   cnt[C];
    __shared__ float red[16];

    const int cam = blockIdx.x;
    const int tid = threadIdx.x;

    for (int i = tid; i < C; i += 1024) cnt[i] = 0;
    __syncthreads();
    if (tid < B) atomicAdd(&cnt[target[tid]], 1);
    __syncthreads();

    float acc = 0.0f;
    if (tid < C) {
        const float* __restrict__ q = partial + cam * K4 + tid * HW4;
        float ssum = 0.0f;
        #pragma unroll 7
        for (int j = 0; j < HW4; ++j) ssum += q[j];
        acc = fabsf(ssum * (1.0f / (float)(B * HW))
                    - (float)cnt[tid] * (1.0f / (float)B));
    }

    #pragma unroll
    for (int off = 32; off > 0; off >>= 1)
        acc += __shfl_down(acc, off, 64);
    if ((tid & 63) == 0) red[tid >> 6] = acc;
    __syncthreads();
    if (tid == 0) {
        float s = 0.0f;
        #pragma unroll
        for (int w = 0; w < 16; ++w) s += red[w];
        out[cam] = s * (1.0f / (float)C);
    }
}

extern "C" void kernel_launch(void* const* d_in, const int* in_sizes, int n_in,
                              void* d_out, int out_size, void* d_ws, size_t ws_size,
                              hipStream_t stream) {
    const float* c0 = (const float*)d_in[0];
    const float* c1 = (const float*)d_in[1];
    const float* c2 = (const float*)d_in[2];
    const float* c3 = (const float*)d_in[3];
    const int*   target = (const int*)d_in[4];

    float* partial = (float*)d_ws;  // 4*49000 floats = 784 KB

    dim3 grid1((K4 + 255) / 256, 4);  // 192 x 4 = 768 blocks, 3/CU
    stage1_kernel<<<grid1, 256, 0, stream>>>(c0, c1, c2, c3, partial);
    stage2_kernel<<<4, 1024, 0, stream>>>(partial, target, (float*)d_out);
}